// Round 4
// baseline (886.300 us; speedup 1.0000x reference)
//
#include <hip/hip_runtime.h>
#include <stdint.h>

#define HH 256
#define WW 1216
#define BB 2
#define CC 64
#define IPIX (HH*WW)
#define NPIX (BB*IPIX)

typedef __attribute__((ext_vector_type(8))) __bf16 bf16x8;
typedef __attribute__((ext_vector_type(4))) float floatx4;

__device__ __forceinline__ float sigm(float x) { return 1.f / (1.f + __expf(-x)); }

// layer order: aff7(24), aff5(16), aff3(8), att7(6), att5(6), att3(6), att1(6), mask(6)
constexpr int LSTART_H[9] = {0,24,40,48,54,60,66,72,78};

// 7x7 tap -> aff plane index (-1 = center, uses g1 with no aff factor)
constexpr int PLANE[49] = {
  0, 1, 2, 3, 4, 5, 6,
  7,24,25,26,27,28, 8,
  9,29,40,41,42,30,10,
 11,31,43,-1,44,32,12,
 13,33,45,46,47,34,14,
 15,35,36,37,38,39,16,
 17,18,19,20,21,22,23};
// 7x7 tap -> kernel class: 0='7', 1='5', 2='3', 3='1'
constexpr int KCLS[49] = {
 0,0,0,0,0,0,0,
 0,1,1,1,1,1,0,
 0,1,2,2,2,1,0,
 0,1,2,3,2,1,0,
 0,1,2,2,2,1,0,
 0,1,1,1,1,1,0,
 0,0,0,0,0,0,0};

struct WPtrs {
    const float* w[8];
    const float* s[8];
    const float* b[8];
};

// ---------------- K0: pack weights into MFMA A-fragment layout (bf16) ----------------
// A-frag for mfma_f32_16x16x32_bf16: lane l holds A[m = l&15][k = (l>>4)*8 + j], j=0..7.
// Global K order: k = tap*64 + c (tap-major). 18 K-steps of 32; M = 80 (5 tiles of 16).
__global__ void k_pack(WPtrs wp, __bf16* __restrict__ wpk,
                       float* __restrict__ s_all, float* __restrict__ b_all) {
    int idx = blockIdx.x * blockDim.x + threadIdx.x;
    if (idx < 18 * 5 * 64) {
        int kk = idx / (5 * 64);
        int r = idx - kk * 5 * 64;
        int t = r >> 6, lane = r & 63;
        int m = t * 16 + (lane & 15);
        int L = 0, o = 0;
        bool valid_m = (m < 78);
        if (valid_m) {
            for (int i = 0; i < 8; i++) if (m >= LSTART_H[i]) { L = i; o = m - LSTART_H[i]; }
        }
        __bf16 vals[8];
        for (int j = 0; j < 8; j++) {
            int k = kk * 32 + ((lane >> 4) * 8) + j;
            int tap = k >> 6, c = k & 63;
            float w = valid_m ? wp.w[L][(o * 64 + c) * 9 + tap] : 0.f;
            vals[j] = (__bf16)w;
        }
        for (int j = 0; j < 8; j++) wpk[(size_t)idx * 8 + j] = vals[j];
    }
    if (idx < 80) {
        int m = idx;
        float sv = 0.f, bv = 0.f;
        if (m < 78) {
            int L = 0, o = 0;
            for (int i = 0; i < 8; i++) if (m >= LSTART_H[i]) { L = i; o = m - LSTART_H[i]; }
            sv = wp.s[L][o]; bv = wp.b[L][o];
        }
        s_all[m] = sv; b_all[m] = bv;
    }
}

// ---------------- K1: conv as implicit GEMM via bf16 MFMA ----------------
// Block: 256 thr = 4 waves; pixel tile 32 wide x 4 high; wave w = row w, 2 N-frags of 16.
// LDS: sf[(row*34 + x)*72 + c], 6*34*72 bf16 = 29376 B -> 4-5 blocks/CU.
__global__ __launch_bounds__(256, 4) void k_conv(const float* __restrict__ feat,
        const float* __restrict__ d00, const __bf16* __restrict__ wpk,
        const float* __restrict__ s_all, const float* __restrict__ b_all,
        __bf16* __restrict__ aff, __bf16* __restrict__ att, __bf16* __restrict__ maskp,
        float* __restrict__ st) {
    __shared__ __bf16 sf[6 * 34 * 72];
    const int tid = threadIdx.x;
    const int x0 = blockIdx.x * 32, y0 = blockIdx.y * 4, b = blockIdx.z;
    const float* fb = feat + (size_t)b * CC * IPIX;

    // stage with register transpose: thread -> (pos, cchunk); 8 strided global dword
    // loads (x-coalesced across lanes), one ds_write_b128 (bank-group stride 9 -> no conflict)
    for (int idx = tid; idx < 204 * 8; idx += 256) {
        int cc = idx / 204;
        int pos = idx - cc * 204;
        int row = pos / 34, x = pos - row * 34;
        int gy = y0 + row - 1, gx = x0 + x - 1;
        bool inb = (gy >= 0) && (gy < HH) && (gx >= 0) && (gx < WW);
        const float* fp = fb + (size_t)(cc * 8) * IPIX + gy * WW + gx;
        bf16x8 pk;
#pragma unroll
        for (int j = 0; j < 8; j++) pk[j] = inb ? (__bf16)fp[(size_t)j * IPIX] : (__bf16)0.f;
        *(bf16x8*)(sf + pos * 72 + cc * 8) = pk;
    }
    __syncthreads();

    const int wave = tid >> 6, lane = tid & 63;
    const int n = lane & 15, g = lane >> 4;

    floatx4 acc[5][2];
#pragma unroll
    for (int t = 0; t < 5; t++)
#pragma unroll
        for (int q = 0; q < 2; q++) acc[t][q] = (floatx4)(0.f);

#pragma unroll 2
    for (int kk = 0; kk < 18; kk++) {
        const int tap = kk >> 1;
        const int dy = tap / 3 - 1, dx = tap % 3 - 1;
        const int c0 = (kk & 1) * 32 + g * 8;
        bf16x8 bfr[2];
        const int rowb = wave + 1 + dy;
        const int colb = 1 + dx + n;
#pragma unroll
        for (int q = 0; q < 2; q++) {
            bfr[q] = *(const bf16x8*)(sf + ((rowb * 34) + colb + q * 16) * 72 + c0);
        }
        bf16x8 afr[5];
        const __bf16* wp0 = wpk + ((size_t)(kk * 5) * 64 + lane) * 8;
#pragma unroll
        for (int t = 0; t < 5; t++) afr[t] = *(const bf16x8*)(wp0 + (size_t)t * 64 * 8);
#pragma unroll
        for (int t = 0; t < 5; t++)
#pragma unroll
            for (int q = 0; q < 2; q++)
                acc[t][q] = __builtin_amdgcn_mfma_f32_16x16x32_bf16(afr[t], bfr[q], acc[t][q], 0, 0, 0);
    }

    // epilogue: m = t*16 + 4*g + reg, pixel = pix_base + q*16
    const int pix_base = b * IPIX + (y0 + wave) * WW + x0 + n;
    float p7[2] = {0,0}, t7[2] = {0,0};
    float p5[2] = {0,0}, t5[2] = {0,0};
    float p3[2] = {0,0}, t3[2] = {0,0};
    float validq[2];
#pragma unroll
    for (int q = 0; q < 2; q++) validq[q] = (d00[pix_base + q * 16] > 0.f) ? 1.f : 0.f;

#pragma unroll
    for (int t = 0; t < 5; t++) {
        const floatx4 sv = *(const floatx4*)(s_all + t * 16 + 4 * g);
        const floatx4 bv = *(const floatx4*)(b_all + t * 16 + 4 * g);
#pragma unroll
        for (int q = 0; q < 2; q++) {
            const int pixq = pix_base + q * 16;
#pragma unroll
            for (int reg = 0; reg < 4; reg++) {
                const int m = t * 16 + 4 * g + reg;
                const float v = fmaf(acc[t][q][reg], sv[reg], bv[reg]);
                if (m < 24)                { p7[q] += fabsf(v); t7[q] += v; }
                else if (m < 40)           { p5[q] += fabsf(v); t5[q] += v; }
                else if (m < 48)           { p3[q] += fabsf(v); t3[q] += v; }
                if (m < 48)      aff[(size_t)m * NPIX + pixq] = (__bf16)v;
                else if (m < 72) att[(size_t)(m - 48) * NPIX + pixq] = (__bf16)sigm(v);
                else if (m < 78) maskp[(size_t)(m - 72) * NPIX + pixq] = (__bf16)(sigm(v) * validq[q]);
            }
        }
    }
#pragma unroll
    for (int q = 0; q < 2; q++) {
        p7[q] += __shfl_xor(p7[q], 16); p7[q] += __shfl_xor(p7[q], 32);
        t7[q] += __shfl_xor(t7[q], 16); t7[q] += __shfl_xor(t7[q], 32);
        p5[q] += __shfl_xor(p5[q], 16); p5[q] += __shfl_xor(p5[q], 32);
        t5[q] += __shfl_xor(t5[q], 16); t5[q] += __shfl_xor(t5[q], 32);
        p3[q] += __shfl_xor(p3[q], 16); p3[q] += __shfl_xor(p3[q], 32);
        t3[q] += __shfl_xor(t3[q], 16); t3[q] += __shfl_xor(t3[q], 32);
    }
    if (g == 0) {
#pragma unroll
        for (int q = 0; q < 2; q++) {
            const int pixq = pix_base + q * 16;
            st[(size_t)0 * NPIX + pixq] = p7[q];
            st[(size_t)1 * NPIX + pixq] = p5[q];
            st[(size_t)2 * NPIX + pixq] = p3[q];
            st[(size_t)3 * NPIX + pixq] = t7[q];
            st[(size_t)4 * NPIX + pixq] = t5[q];
            st[(size_t)5 * NPIX + pixq] = t3[q];
        }
    }
}

// ---------------- K3 (per iter): r_k = att_k/denom; p_k = r_k*dt; base = g0*d0 ----------------
__global__ __launch_bounds__(256) void k_iterA(const __bf16* __restrict__ att, const float* __restrict__ st,
        const float* __restrict__ dt, const float* __restrict__ d0,
        __bf16* __restrict__ pb, float* __restrict__ base, int it) {
    int g = blockIdx.x * blockDim.x + threadIdx.x;
    if (g >= NPIX) return;
    float a7 = (float)att[(size_t)(0 + it) * NPIX + g];
    float a5 = (float)att[(size_t)(6 + it) * NPIX + g];
    float a3 = (float)att[(size_t)(12 + it) * NPIX + g];
    float a1 = (float)att[(size_t)(18 + it) * NPIX + g];
    float S7 = st[(size_t)0 * NPIX + g], S5 = st[(size_t)1 * NPIX + g], S3 = st[(size_t)2 * NPIX + g];
    float T7 = st[(size_t)3 * NPIX + g], T5 = st[(size_t)4 * NPIX + g], T3 = st[(size_t)5 * NPIX + g];
    float denom = a7 * S7 + a5 * S5 + a3 * S3 + a1;   // > 0 since a1 = sigmoid > 0
    float inv = 1.f / denom;
    float r7 = a7 * inv, r5 = a5 * inv, r3 = a3 * inv, r1 = a1 * inv;
    float g0 = 1.f - (r7 * T7 + r5 * T5 + r3 * T3 + r1);
    float dtv = dt[g];
    pb[(size_t)0 * NPIX + g] = (__bf16)(r7 * dtv);
    pb[(size_t)1 * NPIX + g] = (__bf16)(r5 * dtv);
    pb[(size_t)2 * NPIX + g] = (__bf16)(r3 * dtv);
    pb[(size_t)3 * NPIX + g] = (__bf16)(r1 * dtv);
    base[g] = g0 * d0[g];
}

// ---------------- K4 (per iter): 49-tap gather + mask blend ----------------
__global__ __launch_bounds__(256) void k_iterB(const __bf16* __restrict__ aff, const __bf16* __restrict__ pb,
        const float* __restrict__ base, const __bf16* __restrict__ maskp,
        const float* __restrict__ d00,
        float* __restrict__ dtn, int it) {
    __shared__ float sp[4][14 * 38];   // 8+6 rows x 32+6 cols halo tile of p-planes
    const int tid = threadIdx.x;
    const int tx = tid & 31, ty = tid >> 5;
    const int x0 = blockIdx.x * 32, y0 = blockIdx.y * 8, b = blockIdx.z;
    const int ib = b * IPIX;
    for (int idx = tid; idx < 14 * 38; idx += 256) {
        int r = idx / 38, col = idx - r * 38;
        int gy = y0 + r - 3, gx = x0 + col - 3;
        bool inb = (gy >= 0) && (gy < HH) && (gx >= 0) && (gx < WW);
        int q = ib + gy * WW + gx;
#pragma unroll
        for (int k = 0; k < 4; k++) sp[k][idx] = inb ? (float)pb[(size_t)k * NPIX + q] : 0.f;
    }
    __syncthreads();

    const int y = y0 + ty, x = x0 + tx;
    const int pix = ib + y * WW + x;
    float acc = 0.f;
#pragma unroll
    for (int t = 0; t < 49; t++) {
        const int dy = 3 - t / 7, dx = 3 - (t % 7);
        float pv = sp[KCLS[t]][(ty + dy + 3) * 38 + (tx + dx + 3)];
        if (PLANE[t] < 0) {
            acc += pv;
        } else {
            int qy = y + dy, qx = x + dx;
            bool inb = (qy >= 0) && (qy < HH) && (qx >= 0) && (qx < WW);
            float a = inb ? (float)aff[(size_t)PLANE[t] * NPIX + ib + qy * WW + qx] : 0.f;
            acc = fmaf(a, pv, acc);
        }
    }
    float dtv = acc + base[pix];
    float m = (float)maskp[(size_t)it * NPIX + pix];
    float d00v = d00[pix];
    dtv = m * d00v + (1.f - m) * dtv;
    dtn[pix] = dtv;
}

// ---------------- launch ----------------
extern "C" void kernel_launch(void* const* d_in, const int* in_sizes, int n_in,
                              void* d_out, int out_size, void* d_ws, size_t ws_size,
                              hipStream_t stream) {
    const float* feat = (const float*)d_in[0];
    const float* d0   = (const float*)d_in[1];
    const float* d00  = (const float*)d_in[2];
    WPtrs wp;
    for (int l = 0; l < 8; l++) {
        wp.w[l] = (const float*)d_in[3 + 3 * l];
        wp.s[l] = (const float*)d_in[4 + 3 * l];
        wp.b[l] = (const float*)d_in[5 + 3 * l];
    }
    // bf16 planes first, then fp32 planes
    __bf16* wsb   = (__bf16*)d_ws;
    __bf16* aff_b = wsb;                            // 48 planes bf16
    __bf16* att_b = wsb + (size_t)48 * NPIX;        // 24 planes
    __bf16* msk_b = wsb + (size_t)72 * NPIX;        // 6 planes
    __bf16* pb_b  = wsb + (size_t)78 * NPIX;        // 4 planes
    float*  wsf   = (float*)(wsb + (size_t)82 * NPIX);
    float*  st    = wsf;                            // 6 planes fp32
    float*  base  = wsf + (size_t)6 * NPIX;         // 1 plane
    float*  dtA   = wsf + (size_t)7 * NPIX;         // 1 plane (ping)
    __bf16* wpk   = (__bf16*)(wsf + (size_t)8 * NPIX);   // 92160 B packed weights
    float*  s_all = (float*)(wpk + 18 * 5 * 64 * 8);     // 80 fp32
    float*  b_all = s_all + 80;                          // 80 fp32
    float*  dtB   = (float*)d_out;                  // pong = d_out (overwritten before reads)

    hipLaunchKernelGGL(k_pack, dim3(23), dim3(256), 0, stream, wp, wpk, s_all, b_all);
    hipLaunchKernelGGL(k_conv, dim3(WW / 32, HH / 4, BB), dim3(256), 0, stream,
                       feat, d00, wpk, s_all, b_all, aff_b, att_b, msk_b, st);
    // it0: d0 -> dtA; it1: dtA -> d_out; it2: d_out -> dtA; ... it5: dtA -> d_out
    const float* cur = d0;
    for (int it = 0; it < 6; ++it) {
        float* nxt = (it & 1) ? dtB : dtA;
        if (it == 5) nxt = dtB;  // final lands in d_out
        hipLaunchKernelGGL(k_iterA, dim3(NPIX / 256), dim3(256), 0, stream,
                           att_b, st, cur, d0, pb_b, base, it);
        hipLaunchKernelGGL(k_iterB, dim3(WW / 32, HH / 8, BB), dim3(256), 0, stream,
                           aff_b, pb_b, base, msk_b, d00, nxt, it);
        cur = nxt;
    }
}

// Round 5
// 730.726 us; speedup vs baseline: 1.2129x; 1.2129x over previous
//
#include <hip/hip_runtime.h>
#include <stdint.h>

#define HH 256
#define WW 1216
#define BB 2
#define CC 64
#define IPIX (HH*WW)
#define NPIX (BB*IPIX)
// padded planes for gather kernels: 3 halo each side (x right-pad 5 for 8B row alignment)
#define PW 1224
#define PH 262
#define PPIX (PH*PW)              // 320688
#define PLSTRIDE (BB*PPIX)        // 641376

typedef __attribute__((ext_vector_type(8))) __bf16 bf16x8;
typedef __attribute__((ext_vector_type(4))) float floatx4;

__device__ __forceinline__ float sigm(float x) { return 1.f / (1.f + __expf(-x)); }

// layer order: aff7(24), aff5(16), aff3(8), att7(6), att5(6), att3(6), att1(6), mask(6)
constexpr int LSTART_H[9] = {0,24,40,48,54,60,66,72,78};

// 7x7 tap -> aff plane index (-1 = center, uses g1 with no aff factor)
constexpr int PLANE[49] = {
  0, 1, 2, 3, 4, 5, 6,
  7,24,25,26,27,28, 8,
  9,29,40,41,42,30,10,
 11,31,43,-1,44,32,12,
 13,33,45,46,47,34,14,
 15,35,36,37,38,39,16,
 17,18,19,20,21,22,23};
// 7x7 tap -> kernel class: 0='7', 1='5', 2='3', 3='1'
constexpr int KCLS[49] = {
 0,0,0,0,0,0,0,
 0,1,1,1,1,1,0,
 0,1,2,2,2,1,0,
 0,1,2,3,2,1,0,
 0,1,2,2,2,1,0,
 0,1,1,1,1,1,0,
 0,0,0,0,0,0,0};

struct WPtrs {
    const float* w[8];
    const float* s[8];
    const float* b[8];
};

// ---------------- K0: pack weights into MFMA A-fragment layout (bf16) ----------------
__global__ void k_pack(WPtrs wp, __bf16* __restrict__ wpk,
                       float* __restrict__ s_all, float* __restrict__ b_all) {
    int idx = blockIdx.x * blockDim.x + threadIdx.x;
    if (idx < 18 * 5 * 64) {
        int kk = idx / (5 * 64);
        int r = idx - kk * 5 * 64;
        int t = r >> 6, lane = r & 63;
        int m = t * 16 + (lane & 15);
        int L = 0, o = 0;
        bool valid_m = (m < 78);
        if (valid_m) {
            for (int i = 0; i < 8; i++) if (m >= LSTART_H[i]) { L = i; o = m - LSTART_H[i]; }
        }
        __bf16 vals[8];
        for (int j = 0; j < 8; j++) {
            int k = kk * 32 + ((lane >> 4) * 8) + j;
            int tap = k >> 6, c = k & 63;
            float w = valid_m ? wp.w[L][(o * 64 + c) * 9 + tap] : 0.f;
            vals[j] = (__bf16)w;
        }
        for (int j = 0; j < 8; j++) wpk[(size_t)idx * 8 + j] = vals[j];
    }
    if (idx < 80) {
        int m = idx;
        float sv = 0.f, bv = 0.f;
        if (m < 78) {
            int L = 0, o = 0;
            for (int i = 0; i < 8; i++) if (m >= LSTART_H[i]) { L = i; o = m - LSTART_H[i]; }
            sv = wp.s[L][o]; bv = wp.b[L][o];
        }
        s_all[m] = sv; b_all[m] = bv;
    }
}

// ---------------- K0b: zero the pad borders of aff (48) + pb (4) padded planes ----------------
// pad elems per (plane,batch): 6 full rows (6*1224) + 256 interior rows * 8 cols = 9392
__global__ void k_zero_pad(__bf16* __restrict__ aff_p, __bf16* __restrict__ pb_p) {
    const int perPB = 9392;
    int idx = blockIdx.x * blockDim.x + threadIdx.x;
    int total = 52 * BB * perPB;
    if (idx >= total) return;
    int pbi = idx / perPB;
    int e = idx - pbi * perPB;
    int plane = pbi >> 1, b = pbi & 1;
    int r, c;
    if (e < 6 * PW) {
        int rr = e / PW; c = e - rr * PW;
        r = (rr < 3) ? rr : (259 + rr - 3);
    } else {
        int j = e - 6 * PW;
        r = 3 + (j >> 3);
        int c8 = j & 7;
        c = (c8 < 3) ? c8 : (1219 + c8 - 3);
    }
    __bf16* dst = (plane < 48) ? (aff_p + (size_t)plane * PLSTRIDE)
                               : (pb_p + (size_t)(plane - 48) * PLSTRIDE);
    dst[(size_t)b * PPIX + r * PW + c] = (__bf16)0.f;
}

// ---------------- K1: conv as implicit GEMM via bf16 MFMA, weight prefetch pipeline ----------------
// Block: 256 thr = 4 waves; pixel tile 32 wide x 4 high; wave w = row w, 2 N-frags of 16.
// LDS: sf[(row*34 + x)*72 + c], 6*34*72 bf16 = 29376 B.
__global__ __launch_bounds__(256, 3) void k_conv(const float* __restrict__ feat,
        const float* __restrict__ d00, const __bf16* __restrict__ wpk,
        const float* __restrict__ s_all, const float* __restrict__ b_all,
        __bf16* __restrict__ aff_p, __bf16* __restrict__ att, __bf16* __restrict__ maskp,
        float* __restrict__ st) {
    __shared__ __bf16 sf[6 * 34 * 72];
    const int tid = threadIdx.x;
    const int x0 = blockIdx.x * 32, y0 = blockIdx.y * 4, b = blockIdx.z;
    const float* fb = feat + (size_t)b * CC * IPIX;

    for (int idx = tid; idx < 204 * 8; idx += 256) {
        int cc = idx / 204;
        int pos = idx - cc * 204;
        int row = pos / 34, x = pos - row * 34;
        int gy = y0 + row - 1, gx = x0 + x - 1;
        bool inb = (gy >= 0) && (gy < HH) && (gx >= 0) && (gx < WW);
        const float* fp = fb + (size_t)(cc * 8) * IPIX + gy * WW + gx;
        bf16x8 pk;
#pragma unroll
        for (int j = 0; j < 8; j++) pk[j] = inb ? (__bf16)fp[(size_t)j * IPIX] : (__bf16)0.f;
        *(bf16x8*)(sf + pos * 72 + cc * 8) = pk;
    }
    __syncthreads();

    const int wave = tid >> 6, lane = tid & 63;
    const int n = lane & 15, g = lane >> 4;
    const __bf16* wl = wpk + (size_t)lane * 8;

    floatx4 acc[5][2];
#pragma unroll
    for (int t = 0; t < 5; t++)
#pragma unroll
        for (int q = 0; q < 2; q++) acc[t][q] = (floatx4)(0.f);

    // software pipeline: weight A-frags prefetched 2 kk ahead; B-frags 1 ahead
    bf16x8 afrA[5], afrB[5];
#pragma unroll
    for (int t = 0; t < 5; t++) {
        afrA[t] = *(const bf16x8*)(wl + (size_t)(0 * 5 + t) * 64 * 8);
        afrB[t] = *(const bf16x8*)(wl + (size_t)(1 * 5 + t) * 64 * 8);
    }
    bf16x8 bA[2], bB[2];
    {
        const int c0 = 0 * 32 + g * 8;   // kk=0: tap 0, dy=-1, dx=-1
        const int rowb = wave + 0, colb = 0 + n;
#pragma unroll
        for (int q = 0; q < 2; q++) bA[q] = *(const bf16x8*)(sf + ((rowb * 34) + colb + q * 16) * 72 + c0);
    }

#pragma unroll
    for (int kk = 0; kk < 18; kk++) {
        bf16x8* cura = (kk & 1) ? afrB : afrA;
        bf16x8* curb = (kk & 1) ? bB : bA;
        bf16x8* nxtb = (kk & 1) ? bA : bB;
        if (kk < 17) {   // prefetch B-frags for kk+1
            const int tap1 = (kk + 1) >> 1;
            const int dy1 = tap1 / 3 - 1, dx1 = tap1 % 3 - 1;
            const int c01 = ((kk + 1) & 1) * 32 + g * 8;
            const int rowb1 = wave + 1 + dy1, colb1 = 1 + dx1 + n;
#pragma unroll
            for (int q = 0; q < 2; q++)
                nxtb[q] = *(const bf16x8*)(sf + ((rowb1 * 34) + colb1 + q * 16) * 72 + c01);
        }
#pragma unroll
        for (int t = 0; t < 5; t++)
#pragma unroll
            for (int q = 0; q < 2; q++)
                acc[t][q] = __builtin_amdgcn_mfma_f32_16x16x32_bf16(cura[t], curb[q], acc[t][q], 0, 0, 0);
        if (kk < 16) {   // prefetch A-frags for kk+2 into the buffer just consumed
#pragma unroll
            for (int t = 0; t < 5; t++)
                cura[t] = *(const bf16x8*)(wl + (size_t)((kk + 2) * 5 + t) * 64 * 8);
        }
    }

    // epilogue: m = t*16 + 4*g + reg, pixel = base + q*16
    const int pix_base = b * IPIX + (y0 + wave) * WW + x0 + n;                       // unpadded
    const size_t ppx_base = (size_t)b * PPIX + (y0 + wave + 3) * PW + (x0 + n + 3);  // padded
    float p7[2] = {0,0}, t7[2] = {0,0};
    float p5[2] = {0,0}, t5[2] = {0,0};
    float p3[2] = {0,0}, t3[2] = {0,0};
    float validq[2];
#pragma unroll
    for (int q = 0; q < 2; q++) validq[q] = (d00[pix_base + q * 16] > 0.f) ? 1.f : 0.f;

#pragma unroll
    for (int t = 0; t < 5; t++) {
        const floatx4 sv = *(const floatx4*)(s_all + t * 16 + 4 * g);
        const floatx4 bv = *(const floatx4*)(b_all + t * 16 + 4 * g);
#pragma unroll
        for (int q = 0; q < 2; q++) {
            const int pixq = pix_base + q * 16;
#pragma unroll
            for (int reg = 0; reg < 4; reg++) {
                const int m = t * 16 + 4 * g + reg;
                const float v = fmaf(acc[t][q][reg], sv[reg], bv[reg]);
                if (m < 24)                { p7[q] += fabsf(v); t7[q] += v; }
                else if (m < 40)           { p5[q] += fabsf(v); t5[q] += v; }
                else if (m < 48)           { p3[q] += fabsf(v); t3[q] += v; }
                if (m < 48)      aff_p[(size_t)m * PLSTRIDE + ppx_base + q * 16] = (__bf16)v;
                else if (m < 72) att[(size_t)(m - 48) * NPIX + pixq] = (__bf16)sigm(v);
                else if (m < 78) maskp[(size_t)(m - 72) * NPIX + pixq] = (__bf16)(sigm(v) * validq[q]);
            }
        }
    }
#pragma unroll
    for (int q = 0; q < 2; q++) {
        p7[q] += __shfl_xor(p7[q], 16); p7[q] += __shfl_xor(p7[q], 32);
        t7[q] += __shfl_xor(t7[q], 16); t7[q] += __shfl_xor(t7[q], 32);
        p5[q] += __shfl_xor(p5[q], 16); p5[q] += __shfl_xor(p5[q], 32);
        t5[q] += __shfl_xor(t5[q], 16); t5[q] += __shfl_xor(t5[q], 32);
        p3[q] += __shfl_xor(p3[q], 16); p3[q] += __shfl_xor(p3[q], 32);
        t3[q] += __shfl_xor(t3[q], 16); t3[q] += __shfl_xor(t3[q], 32);
    }
    if (g == 0) {
#pragma unroll
        for (int q = 0; q < 2; q++) {
            const int pixq = pix_base + q * 16;
            st[(size_t)0 * NPIX + pixq] = p7[q];
            st[(size_t)1 * NPIX + pixq] = p5[q];
            st[(size_t)2 * NPIX + pixq] = p3[q];
            st[(size_t)3 * NPIX + pixq] = t7[q];
            st[(size_t)4 * NPIX + pixq] = t5[q];
            st[(size_t)5 * NPIX + pixq] = t3[q];
        }
    }
}

// ---------------- K3 (per iter): r_k = att_k/denom; p_k = r_k*dt (padded); base = g0*d0 ----------------
__global__ __launch_bounds__(256) void k_iterA(const __bf16* __restrict__ att, const float* __restrict__ st,
        const float* __restrict__ dt, const float* __restrict__ d0,
        __bf16* __restrict__ pb_p, float* __restrict__ base, int it) {
    int g = blockIdx.x * blockDim.x + threadIdx.x;
    if (g >= NPIX) return;
    float a7 = (float)att[(size_t)(0 + it) * NPIX + g];
    float a5 = (float)att[(size_t)(6 + it) * NPIX + g];
    float a3 = (float)att[(size_t)(12 + it) * NPIX + g];
    float a1 = (float)att[(size_t)(18 + it) * NPIX + g];
    float S7 = st[(size_t)0 * NPIX + g], S5 = st[(size_t)1 * NPIX + g], S3 = st[(size_t)2 * NPIX + g];
    float T7 = st[(size_t)3 * NPIX + g], T5 = st[(size_t)4 * NPIX + g], T3 = st[(size_t)5 * NPIX + g];
    float denom = a7 * S7 + a5 * S5 + a3 * S3 + a1;
    float inv = 1.f / denom;
    float r7 = a7 * inv, r5 = a5 * inv, r3 = a3 * inv, r1 = a1 * inv;
    float g0 = 1.f - (r7 * T7 + r5 * T5 + r3 * T3 + r1);
    float dtv = dt[g];
    int b = g / IPIX;
    int rem = g - b * IPIX;
    int y = rem / WW, x = rem - y * WW;
    size_t pp = (size_t)b * PPIX + (y + 3) * PW + (x + 3);
    pb_p[(size_t)0 * PLSTRIDE + pp] = (__bf16)(r7 * dtv);
    pb_p[(size_t)1 * PLSTRIDE + pp] = (__bf16)(r5 * dtv);
    pb_p[(size_t)2 * PLSTRIDE + pp] = (__bf16)(r3 * dtv);
    pb_p[(size_t)3 * PLSTRIDE + pp] = (__bf16)(r1 * dtv);
    base[g] = g0 * d0[g];
}

// ---------------- K4 (per iter): 49-tap gather + mask blend (padded, no bounds checks) ----------------
__global__ __launch_bounds__(256) void k_iterB(const __bf16* __restrict__ aff_p, const __bf16* __restrict__ pb_p,
        const float* __restrict__ base, const __bf16* __restrict__ maskp,
        const float* __restrict__ d00,
        float* __restrict__ dtn, int it) {
    __shared__ float sp[4][14 * 38];
    const int tid = threadIdx.x;
    const int tx = tid & 31, ty = tid >> 5;
    const int x0 = blockIdx.x * 32, y0 = blockIdx.y * 8, b = blockIdx.z;
    const int ib = b * IPIX;
    for (int idx = tid; idx < 14 * 38; idx += 256) {
        int r = idx / 38, col = idx - r * 38;
        size_t q = (size_t)b * PPIX + (y0 + r) * PW + (x0 + col);
#pragma unroll
        for (int k = 0; k < 4; k++) sp[k][idx] = (float)pb_p[(size_t)k * PLSTRIDE + q];
    }
    __syncthreads();

    const int y = y0 + ty, x = x0 + tx;
    const int pix = ib + y * WW + x;
    const __bf16* ap = aff_p + (size_t)b * PPIX + (y + 3) * PW + (x + 3);
    float acc = 0.f;
#pragma unroll
    for (int t = 0; t < 49; t++) {
        const int dy = 3 - t / 7, dx = 3 - (t % 7);
        float pv = sp[KCLS[t]][(ty + dy + 3) * 38 + (tx + dx + 3)];
        if (PLANE[t] < 0) {
            acc += pv;
        } else {
            float a = (float)ap[(size_t)PLANE[t] * PLSTRIDE + dy * PW + dx];
            acc = fmaf(a, pv, acc);
        }
    }
    float dtv = acc + base[pix];
    float m = (float)maskp[(size_t)it * NPIX + pix];
    float d00v = d00[pix];
    dtv = m * d00v + (1.f - m) * dtv;
    dtn[pix] = dtv;
}

// ---------------- launch ----------------
extern "C" void kernel_launch(void* const* d_in, const int* in_sizes, int n_in,
                              void* d_out, int out_size, void* d_ws, size_t ws_size,
                              hipStream_t stream) {
    const float* feat = (const float*)d_in[0];
    const float* d0   = (const float*)d_in[1];
    const float* d00  = (const float*)d_in[2];
    WPtrs wp;
    for (int l = 0; l < 8; l++) {
        wp.w[l] = (const float*)d_in[3 + 3 * l];
        wp.s[l] = (const float*)d_in[4 + 3 * l];
        wp.b[l] = (const float*)d_in[5 + 3 * l];
    }
    __bf16* wsb   = (__bf16*)d_ws;
    __bf16* aff_p = wsb;                                   // 48 padded planes
    __bf16* pb_p  = aff_p + (size_t)48 * PLSTRIDE;         // 4 padded planes
    __bf16* att_b = pb_p + (size_t)4 * PLSTRIDE;           // 24 planes (unpadded)
    __bf16* msk_b = att_b + (size_t)24 * NPIX;             // 6 planes
    float*  wsf   = (float*)(msk_b + (size_t)6 * NPIX);
    float*  st    = wsf;                                   // 6 planes fp32
    float*  base  = wsf + (size_t)6 * NPIX;                // 1 plane
    float*  dtA   = wsf + (size_t)7 * NPIX;                // 1 plane (ping)
    __bf16* wpk   = (__bf16*)(wsf + (size_t)8 * NPIX);     // 92160 B packed weights
    float*  s_all = (float*)(wpk + 18 * 5 * 64 * 8);
    float*  b_all = s_all + 80;
    float*  dtB   = (float*)d_out;

    hipLaunchKernelGGL(k_pack, dim3(23), dim3(256), 0, stream, wp, wpk, s_all, b_all);
    hipLaunchKernelGGL(k_zero_pad, dim3((52 * BB * 9392 + 255) / 256), dim3(256), 0, stream,
                       aff_p, pb_p);
    hipLaunchKernelGGL(k_conv, dim3(WW / 32, HH / 4, BB), dim3(256), 0, stream,
                       feat, d00, wpk, s_all, b_all, aff_p, att_b, msk_b, st);
    const float* cur = d0;
    for (int it = 0; it < 6; ++it) {
        float* nxt = (it & 1) ? dtB : dtA;
        if (it == 5) nxt = dtB;
        hipLaunchKernelGGL(k_iterA, dim3(NPIX / 256), dim3(256), 0, stream,
                           att_b, st, cur, d0, pb_p, base, it);
        hipLaunchKernelGGL(k_iterB, dim3(WW / 32, HH / 8, BB), dim3(256), 0, stream,
                           aff_p, pb_p, base, msk_b, d00, nxt, it);
        cur = nxt;
    }
}

// Round 6
// 728.192 us; speedup vs baseline: 1.2171x; 1.0035x over previous
//
#include <hip/hip_runtime.h>
#include <stdint.h>

#define HH 256
#define WW 1216
#define BB 2
#define CC 64
#define IPIX (HH*WW)
#define NPIX (BB*IPIX)
// padded planes for aff gather: 3 halo each side (x right-pad 5 for 8B row alignment)
#define PW 1224
#define PH 262
#define PPIX (PH*PW)              // 320688
#define PLSTRIDE (BB*PPIX)        // 641376

typedef __attribute__((ext_vector_type(8))) __bf16 bf16x8;
typedef __attribute__((ext_vector_type(4))) __bf16 bf16x4;
typedef __attribute__((ext_vector_type(4))) float floatx4;

__device__ __forceinline__ float sigm(float x) { return 1.f / (1.f + __expf(-x)); }

// layer order: aff7(24), aff5(16), aff3(8), att7(6), att5(6), att3(6), att1(6), mask(6)
constexpr int LSTART_H[9] = {0,24,40,48,54,60,66,72,78};

// 7x7 tap -> aff plane index (-1 = center, uses g1 with no aff factor)
constexpr int PLANE[49] = {
  0, 1, 2, 3, 4, 5, 6,
  7,24,25,26,27,28, 8,
  9,29,40,41,42,30,10,
 11,31,43,-1,44,32,12,
 13,33,45,46,47,34,14,
 15,35,36,37,38,39,16,
 17,18,19,20,21,22,23};
// 7x7 tap -> kernel class: 0='7', 1='5', 2='3', 3='1' (center: g1); 4 = base plane
constexpr int KCLS[49] = {
 0,0,0,0,0,0,0,
 0,1,1,1,1,1,0,
 0,1,2,2,2,1,0,
 0,1,2,3,2,1,0,
 0,1,2,2,2,1,0,
 0,1,1,1,1,1,0,
 0,0,0,0,0,0,0};

struct WPtrs {
    const float* w[8];
    const float* s[8];
    const float* b[8];
};

// ---------------- K0: pack weights into MFMA A-fragment layout (bf16) ----------------
__global__ void k_pack(WPtrs wp, __bf16* __restrict__ wpk,
                       float* __restrict__ s_all, float* __restrict__ b_all) {
    int idx = blockIdx.x * blockDim.x + threadIdx.x;
    if (idx < 18 * 5 * 64) {
        int kk = idx / (5 * 64);
        int r = idx - kk * 5 * 64;
        int t = r >> 6, lane = r & 63;
        int m = t * 16 + (lane & 15);
        int L = 0, o = 0;
        bool valid_m = (m < 78);
        if (valid_m) {
            for (int i = 0; i < 8; i++) if (m >= LSTART_H[i]) { L = i; o = m - LSTART_H[i]; }
        }
        __bf16 vals[8];
        for (int j = 0; j < 8; j++) {
            int k = kk * 32 + ((lane >> 4) * 8) + j;
            int tap = k >> 6, c = k & 63;
            float w = valid_m ? wp.w[L][(o * 64 + c) * 9 + tap] : 0.f;
            vals[j] = (__bf16)w;
        }
        for (int j = 0; j < 8; j++) wpk[(size_t)idx * 8 + j] = vals[j];
    }
    if (idx < 80) {
        int m = idx;
        float sv = 0.f, bv = 0.f;
        if (m < 78) {
            int L = 0, o = 0;
            for (int i = 0; i < 8; i++) if (m >= LSTART_H[i]) { L = i; o = m - LSTART_H[i]; }
            sv = wp.s[L][o]; bv = wp.b[L][o];
        }
        s_all[m] = sv; b_all[m] = bv;
    }
}

// ---------------- K0b: zero the pad borders of aff (48 padded planes) ----------------
// pad elems per (plane,batch): 6 full rows (6*1224) + 256 interior rows * 8 cols = 9392
__global__ void k_zero_pad(__bf16* __restrict__ aff_p) {
    const int perPB = 9392;
    int idx = blockIdx.x * blockDim.x + threadIdx.x;
    int total = 48 * BB * perPB;
    if (idx >= total) return;
    int pbi = idx / perPB;
    int e = idx - pbi * perPB;
    int plane = pbi >> 1, b = pbi & 1;
    int r, c;
    if (e < 6 * PW) {
        int rr = e / PW; c = e - rr * PW;
        r = (rr < 3) ? rr : (259 + rr - 3);
    } else {
        int j = e - 6 * PW;
        r = 3 + (j >> 3);
        int c8 = j & 7;
        c = (c8 < 3) ? c8 : (1219 + c8 - 3);
    }
    aff_p[(size_t)plane * PLSTRIDE + (size_t)b * PPIX + r * PW + c] = (__bf16)0.f;
}

// ---------------- K1: conv as implicit GEMM via bf16 MFMA ----------------
// Block: 256 thr = 4 waves; pixel tile 32 wide x 4 high; wave w = row w, 2 N-frags of 16.
// LDS: sf[(row*34 + x)*72 + c], 6*34*72 bf16 = 29376 B.
__global__ __launch_bounds__(256, 4) void k_conv(const float* __restrict__ feat,
        const float* __restrict__ d00, const __bf16* __restrict__ wpk,
        const float* __restrict__ s_all, const float* __restrict__ b_all,
        __bf16* __restrict__ aff_p, __bf16* __restrict__ attp, __bf16* __restrict__ maskp,
        float* __restrict__ stp) {
    __shared__ __bf16 sf[6 * 34 * 72];
    const int tid = threadIdx.x;
    const int x0 = blockIdx.x * 32, y0 = blockIdx.y * 4, b = blockIdx.z;
    const float* fb = feat + (size_t)b * CC * IPIX;

    // stage with register transpose: 8 strided global dword loads, one ds_write_b128
    for (int idx = tid; idx < 204 * 8; idx += 256) {
        int cc = idx / 204;
        int pos = idx - cc * 204;
        int row = pos / 34, x = pos - row * 34;
        int gy = y0 + row - 1, gx = x0 + x - 1;
        bool inb = (gy >= 0) && (gy < HH) && (gx >= 0) && (gx < WW);
        const float* fp = fb + (size_t)(cc * 8) * IPIX + gy * WW + gx;
        bf16x8 pk;
#pragma unroll
        for (int j = 0; j < 8; j++) pk[j] = inb ? (__bf16)fp[(size_t)j * IPIX] : (__bf16)0.f;
        *(bf16x8*)(sf + pos * 72 + cc * 8) = pk;
    }
    __syncthreads();

    const int wave = tid >> 6, lane = tid & 63;
    const int n = lane & 15, g = lane >> 4;
    const __bf16* wl = wpk + (size_t)lane * 8;

    floatx4 acc[5][2];
#pragma unroll
    for (int t = 0; t < 5; t++)
#pragma unroll
        for (int q = 0; q < 2; q++) acc[t][q] = (floatx4)(0.f);

#pragma unroll
    for (int kk = 0; kk < 18; kk++) {
        const int tap = kk >> 1;
        const int dy = tap / 3 - 1, dx = tap % 3 - 1;
        const int c0 = (kk & 1) * 32 + g * 8;
        bf16x8 bfr[2];
        const int rowb = wave + 1 + dy;
        const int colb = 1 + dx + n;
#pragma unroll
        for (int q = 0; q < 2; q++)
            bfr[q] = *(const bf16x8*)(sf + ((rowb * 34) + colb + q * 16) * 72 + c0);
        bf16x8 afr[5];
#pragma unroll
        for (int t = 0; t < 5; t++) afr[t] = *(const bf16x8*)(wl + (size_t)((kk * 5) + t) * 64 * 8);
#pragma unroll
        for (int t = 0; t < 5; t++)
#pragma unroll
            for (int q = 0; q < 2; q++)
                acc[t][q] = __builtin_amdgcn_mfma_f32_16x16x32_bf16(afr[t], bfr[q], acc[t][q], 0, 0, 0);
    }

    // epilogue: m = t*16 + 4*g + reg, pixel = pix_base + q*16
    const int pix_base = b * IPIX + (y0 + wave) * WW + x0 + n;                       // unpadded
    const size_t ppx_base = (size_t)b * PPIX + (y0 + wave + 3) * PW + (x0 + n + 3);  // padded
    float p7[2] = {0,0}, t7[2] = {0,0};
    float p5[2] = {0,0}, t5[2] = {0,0};
    float p3[2] = {0,0}, t3[2] = {0,0};
    float validq[2];
#pragma unroll
    for (int q = 0; q < 2; q++) validq[q] = (d00[pix_base + q * 16] > 0.f) ? 1.f : 0.f;

#pragma unroll
    for (int t = 0; t < 5; t++) {
        const floatx4 sv = *(const floatx4*)(s_all + t * 16 + 4 * g);
        const floatx4 bv = *(const floatx4*)(b_all + t * 16 + 4 * g);
#pragma unroll
        for (int q = 0; q < 2; q++) {
            const int pixq = pix_base + q * 16;
#pragma unroll
            for (int reg = 0; reg < 4; reg++) {
                const int m = t * 16 + 4 * g + reg;
                const float v = fmaf(acc[t][q][reg], sv[reg], bv[reg]);
                if (m < 24)                { p7[q] += fabsf(v); t7[q] += v; }
                else if (m < 40)           { p5[q] += fabsf(v); t5[q] += v; }
                else if (m < 48)           { p3[q] += fabsf(v); t3[q] += v; }
                if (m < 48) {
                    aff_p[(size_t)m * PLSTRIDE + ppx_base + q * 16] = (__bf16)v;
                } else if (m < 72) {
                    const int cls = (m - 48) / 6, i = (m - 48) % 6;
                    attp[((size_t)i * NPIX + pixq) * 4 + cls] = (__bf16)sigm(v);
                } else if (m < 78) {
                    maskp[(size_t)(m - 72) * NPIX + pixq] = (__bf16)(sigm(v) * validq[q]);
                }
            }
        }
    }
#pragma unroll
    for (int q = 0; q < 2; q++) {
        p7[q] += __shfl_xor(p7[q], 16); p7[q] += __shfl_xor(p7[q], 32);
        t7[q] += __shfl_xor(t7[q], 16); t7[q] += __shfl_xor(t7[q], 32);
        p5[q] += __shfl_xor(p5[q], 16); p5[q] += __shfl_xor(p5[q], 32);
        t5[q] += __shfl_xor(t5[q], 16); t5[q] += __shfl_xor(t5[q], 32);
        p3[q] += __shfl_xor(p3[q], 16); p3[q] += __shfl_xor(p3[q], 32);
        t3[q] += __shfl_xor(t3[q], 16); t3[q] += __shfl_xor(t3[q], 32);
    }
    if (g == 0) {
#pragma unroll
        for (int q = 0; q < 2; q++) {
            const int pixq = pix_base + q * 16;
            floatx4 s0 = {p7[q], p5[q], p3[q], t7[q]};
            floatx4 s1 = {t5[q], t3[q], 0.f, 0.f};
            *(floatx4*)(stp + (size_t)pixq * 8)     = s0;
            *(floatx4*)(stp + (size_t)pixq * 8 + 4) = s1;
        }
    }
}

// ---------------- K2 (per iter, FUSED): recompute r/g0 on halo tile -> LDS pb, 49-tap gather ----------------
__global__ __launch_bounds__(256) void k_iter(const __bf16* __restrict__ attp,
        const float* __restrict__ stp, const float* __restrict__ dt,
        const float* __restrict__ d0, const __bf16* __restrict__ aff_p,
        const __bf16* __restrict__ maskp, const float* __restrict__ d00,
        float* __restrict__ dtn, int it) {
    __shared__ float sp[5][14 * 38];   // p7,p5,p3,p1, g0*d0 on 8+6 x 32+6 halo tile
    const int tid = threadIdx.x;
    const int tx = tid & 31, ty = tid >> 5;
    const int x0 = blockIdx.x * 32, y0 = blockIdx.y * 8, b = blockIdx.z;
    const int ib = b * IPIX;

    for (int idx = tid; idx < 14 * 38; idx += 256) {
        int r = idx / 38, col = idx - r * 38;
        int gy = y0 + r - 3, gx = x0 + col - 3;
        float v7 = 0.f, v5 = 0.f, v3 = 0.f, v1 = 0.f, vb = 0.f;
        if (gy >= 0 && gy < HH && gx >= 0 && gx < WW) {
            int q = ib + gy * WW + gx;
            bf16x4 a = *(const bf16x4*)(attp + ((size_t)it * NPIX + q) * 4);
            float a7 = (float)a[0], a5 = (float)a[1], a3 = (float)a[2], a1 = (float)a[3];
            const floatx4 s0 = *(const floatx4*)(stp + (size_t)q * 8);
            const floatx4 s1 = *(const floatx4*)(stp + (size_t)q * 8 + 4);
            float S7 = s0[0], S5 = s0[1], S3 = s0[2], T7 = s0[3], T5 = s1[0], T3 = s1[1];
            float denom = a7 * S7 + a5 * S5 + a3 * S3 + a1;   // > 0: a1 = sigmoid > 0
            float inv = 1.f / denom;
            float r7 = a7 * inv, r5 = a5 * inv, r3 = a3 * inv, r1 = a1 * inv;
            float g0 = 1.f - (r7 * T7 + r5 * T5 + r3 * T3 + r1);
            float dtv = dt[q];
            v7 = r7 * dtv; v5 = r5 * dtv; v3 = r3 * dtv; v1 = r1 * dtv;
            vb = g0 * d0[q];
        }
        sp[0][idx] = v7; sp[1][idx] = v5; sp[2][idx] = v3; sp[3][idx] = v1; sp[4][idx] = vb;
    }
    __syncthreads();

    const int y = y0 + ty, x = x0 + tx;
    const int pix = ib + y * WW + x;
    const __bf16* ap = aff_p + (size_t)b * PPIX + (y + 3) * PW + (x + 3);
    float acc = sp[4][(ty + 3) * 38 + (tx + 3)];   // g0*d0
#pragma unroll
    for (int t = 0; t < 49; t++) {
        const int dy = 3 - t / 7, dx = 3 - (t % 7);
        float pv = sp[KCLS[t]][(ty + dy + 3) * 38 + (tx + dx + 3)];
        if (PLANE[t] < 0) {
            acc += pv;
        } else {
            float a = (float)ap[(size_t)PLANE[t] * PLSTRIDE + dy * PW + dx];
            acc = fmaf(a, pv, acc);
        }
    }
    float m = (float)maskp[(size_t)it * NPIX + pix];
    float d00v = d00[pix];
    float dtv = m * d00v + (1.f - m) * acc;
    dtn[pix] = dtv;
}

// ---------------- launch ----------------
extern "C" void kernel_launch(void* const* d_in, const int* in_sizes, int n_in,
                              void* d_out, int out_size, void* d_ws, size_t ws_size,
                              hipStream_t stream) {
    const float* feat = (const float*)d_in[0];
    const float* d0   = (const float*)d_in[1];
    const float* d00  = (const float*)d_in[2];
    WPtrs wp;
    for (int l = 0; l < 8; l++) {
        wp.w[l] = (const float*)d_in[3 + 3 * l];
        wp.s[l] = (const float*)d_in[4 + 3 * l];
        wp.b[l] = (const float*)d_in[5 + 3 * l];
    }
    __bf16* wsb   = (__bf16*)d_ws;
    __bf16* aff_p = wsb;                                   // 48 padded planes bf16
    __bf16* attp  = aff_p + (size_t)48 * PLSTRIDE;         // 6*NPIX bf16x4 (packed per-iter att)
    __bf16* msk_b = attp + (size_t)6 * NPIX * 4;           // 6 planes bf16
    float*  wsf   = (float*)(msk_b + (size_t)6 * NPIX);
    float*  stp   = wsf;                                   // NPIX * 8 fp32 (S7,S5,S3,T7,T5,T3,pad2)
    float*  dtA   = wsf + (size_t)8 * NPIX;                // 1 fp32 plane (ping)
    __bf16* wpk   = (__bf16*)(wsf + (size_t)9 * NPIX);     // 92160 B packed weights
    float*  s_all = (float*)(wpk + 18 * 5 * 64 * 8);
    float*  b_all = s_all + 80;
    float*  dtB   = (float*)d_out;                         // pong (fully overwritten before reads)

    hipLaunchKernelGGL(k_pack, dim3(23), dim3(256), 0, stream, wp, wpk, s_all, b_all);
    hipLaunchKernelGGL(k_zero_pad, dim3((48 * BB * 9392 + 255) / 256), dim3(256), 0, stream, aff_p);
    hipLaunchKernelGGL(k_conv, dim3(WW / 32, HH / 4, BB), dim3(256), 0, stream,
                       feat, d00, wpk, s_all, b_all, aff_p, attp, msk_b, stp);
    const float* cur = d0;
    for (int it = 0; it < 6; ++it) {
        float* nxt = (it & 1) ? dtB : dtA;
        if (it == 5) nxt = dtB;
        hipLaunchKernelGGL(k_iter, dim3(WW / 32, HH / 8, BB), dim3(256), 0, stream,
                           attp, stp, cur, d0, aff_p, msk_b, d00, nxt, it);
        cur = nxt;
    }
}

// Round 7
// 722.921 us; speedup vs baseline: 1.2260x; 1.0073x over previous
//
#include <hip/hip_runtime.h>
#include <hip/hip_fp16.h>
#include <stdint.h>

#define HH 256
#define WW 1216
#define BB 2
#define CC 64
#define IPIX (HH*WW)
#define NPIX (BB*IPIX)
// padded aff planes: left pad 32 (64B-aligned rows), right pad, 3-row halo top/bottom
#define PW 1280
#define PH 262
#define PPIX (PH*PW)               // 335360
#define PLSTRIDE (BB*PPIX)         // 670720
#define XOFF 32

typedef __attribute__((ext_vector_type(8))) __bf16 bf16x8;
typedef __attribute__((ext_vector_type(4))) __bf16 bf16x4;
typedef __attribute__((ext_vector_type(4))) float floatx4;
typedef __attribute__((ext_vector_type(4))) _Float16 half4;

__device__ __forceinline__ float sigm(float x) { return 1.f / (1.f + __expf(-x)); }

// layer order: aff7(24), aff5(16), aff3(8), att7(6), att5(6), att3(6), att1(6), mask(6)
constexpr int LSTART_H[9] = {0,24,40,48,54,60,66,72,78};

// 7x7 tap -> aff plane index (-1 = center, uses g1 with no aff factor)
constexpr int PLANE[49] = {
  0, 1, 2, 3, 4, 5, 6,
  7,24,25,26,27,28, 8,
  9,29,40,41,42,30,10,
 11,31,43,-1,44,32,12,
 13,33,45,46,47,34,14,
 15,35,36,37,38,39,16,
 17,18,19,20,21,22,23};
// 7x7 tap -> kernel class: 0='7', 1='5', 2='3', 3='1'
constexpr int KCLS[49] = {
 0,0,0,0,0,0,0,
 0,1,1,1,1,1,0,
 0,1,2,2,2,1,0,
 0,1,2,3,2,1,0,
 0,1,2,2,2,1,0,
 0,1,1,1,1,1,0,
 0,0,0,0,0,0,0};

struct WPtrs {
    const float* w[8];
    const float* s[8];
    const float* b[8];
};

// ---------------- K0: pack weights into MFMA A-fragment layout (bf16) ----------------
__global__ void k_pack(WPtrs wp, __bf16* __restrict__ wpk,
                       float* __restrict__ s_all, float* __restrict__ b_all) {
    int idx = blockIdx.x * blockDim.x + threadIdx.x;
    if (idx < 18 * 5 * 64) {
        int kk = idx / (5 * 64);
        int r = idx - kk * 5 * 64;
        int t = r >> 6, lane = r & 63;
        int m = t * 16 + (lane & 15);
        int L = 0, o = 0;
        bool valid_m = (m < 78);
        if (valid_m) {
            for (int i = 0; i < 8; i++) if (m >= LSTART_H[i]) { L = i; o = m - LSTART_H[i]; }
        }
        __bf16 vals[8];
        for (int j = 0; j < 8; j++) {
            int k = kk * 32 + ((lane >> 4) * 8) + j;
            int tap = k >> 6, c = k & 63;
            float w = valid_m ? wp.w[L][(o * 64 + c) * 9 + tap] : 0.f;
            vals[j] = (__bf16)w;
        }
        for (int j = 0; j < 8; j++) wpk[(size_t)idx * 8 + j] = vals[j];
    }
    if (idx < 80) {
        int m = idx;
        float sv = 0.f, bv = 0.f;
        if (m < 78) {
            int L = 0, o = 0;
            for (int i = 0; i < 8; i++) if (m >= LSTART_H[i]) { L = i; o = m - LSTART_H[i]; }
            sv = wp.s[L][o]; bv = wp.b[L][o];
        }
        s_all[m] = sv; b_all[m] = bv;
    }
}

// ---------------- K0b: zero the pad borders of aff (48 padded planes) ----------------
// per (plane,batch): 6 full rows (6*PW) + 256 interior rows * 16 cols (24..31, 1248..1255)
__global__ void k_zero_pad(__bf16* __restrict__ aff_p) {
    const int perPB = 6 * PW + 256 * 16;   // 11776
    int idx = blockIdx.x * blockDim.x + threadIdx.x;
    int total = 48 * BB * perPB;
    if (idx >= total) return;
    int pbi = idx / perPB;
    int e = idx - pbi * perPB;
    int plane = pbi >> 1, b = pbi & 1;
    int r, c;
    if (e < 6 * PW) {
        int rr = e / PW; c = e - rr * PW;
        r = (rr < 3) ? rr : (259 + rr - 3);
    } else {
        int j = e - 6 * PW;
        r = 3 + (j >> 4);
        int c16 = j & 15;
        c = (c16 < 8) ? (24 + c16) : (1248 + c16 - 8);
    }
    aff_p[(size_t)plane * PLSTRIDE + (size_t)b * PPIX + r * PW + c] = (__bf16)0.f;
}

// ---------------- K1: conv as implicit GEMM via bf16 MFMA, LDS-transposed epilogue ----------------
// Block: 256 thr = 4 waves; pixel tile 32 wide x 4 high; wave w = row w, 2 N-frags of 16.
// LDS: sf[(row*34 + x)*72 + c], 6*34*72 bf16 = 29376 B; reused as tb[m*132+px] (20592 B).
__global__ __launch_bounds__(256, 4) void k_conv(const float* __restrict__ feat,
        const float* __restrict__ d00, const __bf16* __restrict__ wpk,
        const float* __restrict__ s_all, const float* __restrict__ b_all,
        __bf16* __restrict__ aff_p, __bf16* __restrict__ attp, __bf16* __restrict__ maskp,
        float* __restrict__ stp) {
    __shared__ __bf16 sh[6 * 34 * 72];
    const int tid = threadIdx.x;
    const int x0 = blockIdx.x * 32, y0 = blockIdx.y * 4, b = blockIdx.z;
    const float* fb = feat + (size_t)b * CC * IPIX;

    // stage with register transpose: 8 strided global dword loads, one ds_write_b128
    for (int idx = tid; idx < 204 * 8; idx += 256) {
        int cc = idx / 204;
        int pos = idx - cc * 204;
        int row = pos / 34, x = pos - row * 34;
        int gy = y0 + row - 1, gx = x0 + x - 1;
        bool inb = (gy >= 0) && (gy < HH) && (gx >= 0) && (gx < WW);
        const float* fp = fb + (size_t)(cc * 8) * IPIX + gy * WW + gx;
        bf16x8 pk;
#pragma unroll
        for (int j = 0; j < 8; j++) pk[j] = inb ? (__bf16)fp[(size_t)j * IPIX] : (__bf16)0.f;
        *(bf16x8*)(sh + pos * 72 + cc * 8) = pk;
    }
    __syncthreads();

    const int wave = tid >> 6, lane = tid & 63;
    const int n = lane & 15, g = lane >> 4;
    const __bf16* wl = wpk + (size_t)lane * 8;

    floatx4 acc[5][2];
#pragma unroll
    for (int t = 0; t < 5; t++)
#pragma unroll
        for (int q = 0; q < 2; q++) acc[t][q] = (floatx4)(0.f);

#pragma unroll
    for (int kk = 0; kk < 18; kk++) {
        const int tap = kk >> 1;
        const int dy = tap / 3 - 1, dx = tap % 3 - 1;
        const int c0 = (kk & 1) * 32 + g * 8;
        bf16x8 bfr[2];
        const int rowb = wave + 1 + dy;
        const int colb = 1 + dx + n;
#pragma unroll
        for (int q = 0; q < 2; q++)
            bfr[q] = *(const bf16x8*)(sh + ((rowb * 34) + colb + q * 16) * 72 + c0);
        bf16x8 afr[5];
#pragma unroll
        for (int t = 0; t < 5; t++) afr[t] = *(const bf16x8*)(wl + (size_t)((kk * 5) + t) * 64 * 8);
#pragma unroll
        for (int t = 0; t < 5; t++)
#pragma unroll
            for (int q = 0; q < 2; q++)
                acc[t][q] = __builtin_amdgcn_mfma_f32_16x16x32_bf16(afr[t], bfr[q], acc[t][q], 0, 0, 0);
    }

    __syncthreads();   // all waves done reading sh; safe to alias as transpose buffer

    // phase 1: scale/bias + stats; write bf16 results into LDS tb[m*132 + wave*32 + n + 16q]
    const int pix_base = b * IPIX + (y0 + wave) * WW + x0 + n;
    float p7[2] = {0,0}, t7[2] = {0,0};
    float p5[2] = {0,0}, t5[2] = {0,0};
    float p3[2] = {0,0}, t3[2] = {0,0};

#pragma unroll
    for (int t = 0; t < 5; t++) {
        const floatx4 sv = *(const floatx4*)(s_all + t * 16 + 4 * g);
        const floatx4 bv = *(const floatx4*)(b_all + t * 16 + 4 * g);
#pragma unroll
        for (int q = 0; q < 2; q++) {
#pragma unroll
            for (int reg = 0; reg < 4; reg++) {
                const int m = t * 16 + 4 * g + reg;
                const float v = fmaf(acc[t][q][reg], sv[reg], bv[reg]);
                if (m < 24)                { p7[q] += fabsf(v); t7[q] += v; }
                else if (m < 40)           { p5[q] += fabsf(v); t5[q] += v; }
                else if (m < 48)           { p3[q] += fabsf(v); t3[q] += v; }
                const float outv = (m < 48) ? v : sigm(v);
                sh[m * 132 + wave * 32 + n + q * 16] = (__bf16)outv;
            }
        }
    }
    // per-pixel stats via cross-lane butterfly over g, store packed (32 B/px, coalesced)
#pragma unroll
    for (int q = 0; q < 2; q++) {
        p7[q] += __shfl_xor(p7[q], 16); p7[q] += __shfl_xor(p7[q], 32);
        t7[q] += __shfl_xor(t7[q], 16); t7[q] += __shfl_xor(t7[q], 32);
        p5[q] += __shfl_xor(p5[q], 16); p5[q] += __shfl_xor(p5[q], 32);
        t5[q] += __shfl_xor(t5[q], 16); t5[q] += __shfl_xor(t5[q], 32);
        p3[q] += __shfl_xor(p3[q], 16); p3[q] += __shfl_xor(p3[q], 32);
        t3[q] += __shfl_xor(t3[q], 16); t3[q] += __shfl_xor(t3[q], 32);
    }
    if (g == 0) {
#pragma unroll
        for (int q = 0; q < 2; q++) {
            const int pixq = pix_base + q * 16;
            floatx4 s0 = {p7[q], p5[q], p3[q], t7[q]};
            floatx4 s1 = {t5[q], t3[q], 0.f, 0.f};
            *(floatx4*)(stp + (size_t)pixq * 8)     = s0;
            *(floatx4*)(stp + (size_t)pixq * 8 + 4) = s1;
        }
    }
    __syncthreads();

    // phase 2: transpose-read, fully coalesced stores (64B-aligned lines)
    const int px = tid & 127;            // 4 rows x 32 cols
    const int grp = tid >> 7;            // 0/1
    const int prow = px >> 5, pcol = px & 31;
    const size_t ppx = (size_t)b * PPIX + (y0 + prow + 3) * PW + (x0 + pcol + XOFF);
    const int pix = b * IPIX + (y0 + prow) * WW + x0 + pcol;
#pragma unroll
    for (int m = 0; m < 48; m += 2) {
        aff_p[(size_t)(m + grp) * PLSTRIDE + ppx] = sh[(m + grp) * 132 + px];
    }
    const float d00v = d00[pix];
    const float valid = (d00v > 0.f) ? 1.f : 0.f;
#pragma unroll
    for (int j = 0; j < 6; j += 2) {
        const int it = j + grp;
        bf16x4 av = { sh[(48 + it) * 132 + px], sh[(54 + it) * 132 + px],
                      sh[(60 + it) * 132 + px], sh[(66 + it) * 132 + px] };
        *(bf16x4*)(attp + ((size_t)it * NPIX + pix) * 4) = av;
        maskp[(size_t)it * NPIX + pix] = (__bf16)((float)sh[(72 + it) * 132 + px] * valid);
    }
}

// ---------------- K2 (once): per-pixel, per-iter guide ratios r_k and g0*d0 ----------------
__global__ __launch_bounds__(256) void k_rg(const __bf16* __restrict__ attp,
        const float* __restrict__ stp, const float* __restrict__ d0,
        _Float16* __restrict__ rp, float* __restrict__ gd) {
    int g = blockIdx.x * blockDim.x + threadIdx.x;
    if (g >= NPIX) return;
    const floatx4 s0 = *(const floatx4*)(stp + (size_t)g * 8);
    const floatx4 s1 = *(const floatx4*)(stp + (size_t)g * 8 + 4);
    const float S7 = s0[0], S5 = s0[1], S3 = s0[2], T7 = s0[3], T5 = s1[0], T3 = s1[1];
    const float d0v = d0[g];
#pragma unroll
    for (int it = 0; it < 6; it++) {
        bf16x4 a = *(const bf16x4*)(attp + ((size_t)it * NPIX + g) * 4);
        float a7 = (float)a[0], a5 = (float)a[1], a3 = (float)a[2], a1 = (float)a[3];
        float denom = a7 * S7 + a5 * S5 + a3 * S3 + a1;   // > 0: a1 = sigmoid > 0
        float inv = 1.f / denom;
        float r7 = a7 * inv, r5 = a5 * inv, r3 = a3 * inv, r1 = a1 * inv;
        float g0 = 1.f - (r7 * T7 + r5 * T5 + r3 * T3 + r1);
        half4 rv = {(_Float16)r7, (_Float16)r5, (_Float16)r3, (_Float16)r1};
        *(half4*)(rp + ((size_t)it * NPIX + g) * 4) = rv;
        gd[(size_t)it * NPIX + g] = g0 * d0v;
    }
}

// ---------------- K3 (per iter): stage p-planes in LDS, hoisted 49-tap gather ----------------
__global__ __launch_bounds__(256) void k_iter(const _Float16* __restrict__ rp,
        const float* __restrict__ gd, const float* __restrict__ dt,
        const __bf16* __restrict__ aff_p, const __bf16* __restrict__ maskp,
        const float* __restrict__ d00,
        float* __restrict__ dtn, int it) {
    __shared__ float sp[5][14 * 38];   // p7,p5,p3,p1, g0*d0 on (8+6) x (32+6) halo tile
    const int tid = threadIdx.x;
    const int tx = tid & 31, ty = tid >> 5;
    const int x0 = blockIdx.x * 32, y0 = blockIdx.y * 8, b = blockIdx.z;
    const int ib = b * IPIX;

    for (int idx = tid; idx < 14 * 38; idx += 256) {
        int r = idx / 38, col = idx - r * 38;
        int gy = y0 + r - 3, gx = x0 + col - 3;
        float v7 = 0.f, v5 = 0.f, v3 = 0.f, v1 = 0.f, vb = 0.f;
        if (gy >= 0 && gy < HH && gx >= 0 && gx < WW) {
            int q = ib + gy * WW + gx;
            half4 rv = *(const half4*)(rp + ((size_t)it * NPIX + q) * 4);
            float dtv = dt[q];
            v7 = (float)rv[0] * dtv; v5 = (float)rv[1] * dtv;
            v3 = (float)rv[2] * dtv; v1 = (float)rv[3] * dtv;
            vb = gd[(size_t)it * NPIX + q];
        }
        sp[0][idx] = v7; sp[1][idx] = v5; sp[2][idx] = v3; sp[3][idx] = v1; sp[4][idx] = vb;
    }
    __syncthreads();

    const int y = y0 + ty, x = x0 + tx;
    const int pix = ib + y * WW + x;
    const __bf16* ap = aff_p + (size_t)b * PPIX + (y + 3) * PW + (x + XOFF);

    // hoist all 48 aff loads (one waitcnt, max MLP)
    float av[48];
    {
        int s = 0;
#pragma unroll
        for (int t = 0; t < 49; t++) {
            if (PLANE[t] >= 0) {
                const int dy = 3 - t / 7, dx = 3 - (t % 7);
                av[s++] = (float)ap[(ptrdiff_t)PLANE[t] * PLSTRIDE + dy * PW + dx];
            }
        }
    }
    // 4-way accumulator tree
    float ac0 = sp[4][(ty + 3) * 38 + (tx + 3)];   // g0*d0
    float ac1 = 0.f, ac2 = 0.f, ac3 = 0.f;
    {
        int s = 0;
#pragma unroll
        for (int t = 0; t < 49; t++) {
            const int dy = 3 - t / 7, dx = 3 - (t % 7);
            float pv = sp[KCLS[t]][(ty + dy + 3) * 38 + (tx + dx + 3)];
            if (PLANE[t] < 0) {
                ac1 += pv;
            } else {
                float a = av[s++];
                switch (t & 3) {
                    case 0: ac0 = fmaf(a, pv, ac0); break;
                    case 1: ac1 = fmaf(a, pv, ac1); break;
                    case 2: ac2 = fmaf(a, pv, ac2); break;
                    default: ac3 = fmaf(a, pv, ac3); break;
                }
            }
        }
    }
    float acc = (ac0 + ac1) + (ac2 + ac3);
    float m = (float)maskp[(size_t)it * NPIX + pix];
    float dtv = m * d00[pix] + (1.f - m) * acc;
    dtn[pix] = dtv;
}

// ---------------- launch ----------------
extern "C" void kernel_launch(void* const* d_in, const int* in_sizes, int n_in,
                              void* d_out, int out_size, void* d_ws, size_t ws_size,
                              hipStream_t stream) {
    const float* feat = (const float*)d_in[0];
    const float* d0   = (const float*)d_in[1];
    const float* d00  = (const float*)d_in[2];
    WPtrs wp;
    for (int l = 0; l < 8; l++) {
        wp.w[l] = (const float*)d_in[3 + 3 * l];
        wp.s[l] = (const float*)d_in[4 + 3 * l];
        wp.b[l] = (const float*)d_in[5 + 3 * l];
    }
    __bf16*   wsb   = (__bf16*)d_ws;
    __bf16*   aff_p = wsb;                                  // 48 padded planes bf16 (64.4 MB)
    __bf16*   attp  = aff_p + (size_t)48 * PLSTRIDE;        // 6*NPIX bf16x4
    __bf16*   msk_b = attp + (size_t)6 * NPIX * 4;          // 6 planes bf16
    _Float16* rp    = (_Float16*)(msk_b + (size_t)6 * NPIX); // 6*NPIX fp16x4
    float*    wsf   = (float*)(rp + (size_t)6 * NPIX * 4);
    float*    gd    = wsf;                                  // 6*NPIX fp32
    float*    stp   = wsf + (size_t)6 * NPIX;               // NPIX*8 fp32
    float*    dtA   = stp + (size_t)8 * NPIX;               // 1 fp32 plane (ping)
    __bf16*   wpk   = (__bf16*)(dtA + (size_t)NPIX);        // 92160 B packed weights
    float*    s_all = (float*)(wpk + 18 * 5 * 64 * 8);
    float*    b_all = s_all + 80;
    float*    dtB   = (float*)d_out;                        // pong (overwritten before reads)

    hipLaunchKernelGGL(k_pack, dim3(23), dim3(256), 0, stream, wp, wpk, s_all, b_all);
    hipLaunchKernelGGL(k_zero_pad, dim3((48 * BB * (6 * PW + 256 * 16) + 255) / 256), dim3(256),
                       0, stream, aff_p);
    hipLaunchKernelGGL(k_conv, dim3(WW / 32, HH / 4, BB), dim3(256), 0, stream,
                       feat, d00, wpk, s_all, b_all, aff_p, attp, msk_b, stp);
    hipLaunchKernelGGL(k_rg, dim3(NPIX / 256), dim3(256), 0, stream,
                       attp, stp, d0, rp, gd);
    const float* cur = d0;
    for (int it = 0; it < 6; ++it) {
        float* nxt = (it & 1) ? dtB : dtA;
        if (it == 5) nxt = dtB;
        hipLaunchKernelGGL(k_iter, dim3(WW / 32, HH / 8, BB), dim3(256), 0, stream,
                           rp, gd, cur, aff_p, msk_b, d00, nxt, it);
        cur = nxt;
    }
}

// Round 8
// 522.485 us; speedup vs baseline: 1.6963x; 1.3836x over previous
//
#include <hip/hip_runtime.h>
#include <hip/hip_fp16.h>
#include <stdint.h>

#define HH 256
#define WW 1216
#define BB 2
#define CC 64
#define IPIX (HH*WW)
#define NPIX (BB*IPIX)
// padded aff planes: left pad 32 (64B-aligned rows), right pad, 3-row halo top/bottom
#define PW 1280
#define PH 262
#define PPIX (PH*PW)               // 335360
#define PLSTRIDE (BB*PPIX)         // 670720
#define XOFF 32

typedef __attribute__((ext_vector_type(8))) __bf16 bf16x8;
typedef __attribute__((ext_vector_type(4))) __bf16 bf16x4;
typedef __attribute__((ext_vector_type(4))) float floatx4;
typedef __attribute__((ext_vector_type(4))) _Float16 half4;

__device__ __forceinline__ float sigm(float x) { return 1.f / (1.f + __expf(-x)); }

// layer order: aff7(24), aff5(16), aff3(8), att7(6), att5(6), att3(6), att1(6), mask(6)
constexpr int LSTART_H[9] = {0,24,40,48,54,60,66,72,78};

// 7x7 tap -> aff plane index (-1 = center, uses g1 with no aff factor)
constexpr int PLANE[49] = {
  0, 1, 2, 3, 4, 5, 6,
  7,24,25,26,27,28, 8,
  9,29,40,41,42,30,10,
 11,31,43,-1,44,32,12,
 13,33,45,46,47,34,14,
 15,35,36,37,38,39,16,
 17,18,19,20,21,22,23};
// 7x7 tap -> kernel class: 0='7', 1='5', 2='3', 3='1'
constexpr int KCLS[49] = {
 0,0,0,0,0,0,0,
 0,1,1,1,1,1,0,
 0,1,2,2,2,1,0,
 0,1,2,3,2,1,0,
 0,1,2,2,2,1,0,
 0,1,1,1,1,1,0,
 0,0,0,0,0,0,0};
// the 48 non-center taps in order
constexpr int TAPNC[48] = {
  0,1,2,3,4,5,6,7,8,9,10,11,12,13,14,15,16,17,18,19,20,21,22,23,
  25,26,27,28,29,30,31,32,33,34,35,36,37,38,39,40,41,42,43,44,45,46,47,48};

struct WPtrs {
    const float* w[8];
    const float* s[8];
    const float* b[8];
};

// ---------------- K0: pack weights into MFMA A-fragment layout (bf16) ----------------
__global__ void k_pack(WPtrs wp, __bf16* __restrict__ wpk,
                       float* __restrict__ s_all, float* __restrict__ b_all) {
    int idx = blockIdx.x * blockDim.x + threadIdx.x;
    if (idx < 18 * 5 * 64) {
        int kk = idx / (5 * 64);
        int r = idx - kk * 5 * 64;
        int t = r >> 6, lane = r & 63;
        int m = t * 16 + (lane & 15);
        int L = 0, o = 0;
        bool valid_m = (m < 78);
        if (valid_m) {
            for (int i = 0; i < 8; i++) if (m >= LSTART_H[i]) { L = i; o = m - LSTART_H[i]; }
        }
        __bf16 vals[8];
        for (int j = 0; j < 8; j++) {
            int k = kk * 32 + ((lane >> 4) * 8) + j;
            int tap = k >> 6, c = k & 63;
            float w = valid_m ? wp.w[L][(o * 64 + c) * 9 + tap] : 0.f;
            vals[j] = (__bf16)w;
        }
        for (int j = 0; j < 8; j++) wpk[(size_t)idx * 8 + j] = vals[j];
    }
    if (idx < 80) {
        int m = idx;
        float sv = 0.f, bv = 0.f;
        if (m < 78) {
            int L = 0, o = 0;
            for (int i = 0; i < 8; i++) if (m >= LSTART_H[i]) { L = i; o = m - LSTART_H[i]; }
            sv = wp.s[L][o]; bv = wp.b[L][o];
        }
        s_all[m] = sv; b_all[m] = bv;
    }
}

// ---------------- K0b: zero the pad borders of aff (48 padded planes) ----------------
__global__ void k_zero_pad(__bf16* __restrict__ aff_p) {
    const int perPB = 6 * PW + 256 * 16;   // 11776
    int idx = blockIdx.x * blockDim.x + threadIdx.x;
    int total = 48 * BB * perPB;
    if (idx >= total) return;
    int pbi = idx / perPB;
    int e = idx - pbi * perPB;
    int plane = pbi >> 1, b = pbi & 1;
    int r, c;
    if (e < 6 * PW) {
        int rr = e / PW; c = e - rr * PW;
        r = (rr < 3) ? rr : (259 + rr - 3);
    } else {
        int j = e - 6 * PW;
        r = 3 + (j >> 4);
        int c16 = j & 15;
        c = (c16 < 8) ? (24 + c16) : (1248 + c16 - 8);
    }
    aff_p[(size_t)plane * PLSTRIDE + (size_t)b * PPIX + r * PW + c] = (__bf16)0.f;
}

// ---------------- K0c: feature fp32 NCHW -> bf16 (b,y,x,[c]) channel-packed ----------------
__global__ __launch_bounds__(256) void k_cvt(const float* __restrict__ feat,
                                             __bf16* __restrict__ fpk) {
    const int x = blockIdx.x * 64 + (threadIdx.x & 63);
    const int half = threadIdx.x >> 6;            // 0..3
    const int y = blockIdx.y, b = blockIdx.z;
    const float* fb = feat + (size_t)b * CC * IPIX + (size_t)y * WW + x;
    __bf16* op = fpk + ((size_t)(b * IPIX + y * WW + x) << 6);
#pragma unroll
    for (int h = 0; h < 2; h++) {
        const int cg = half + h * 4;              // channel group of 8
        bf16x8 pk;
#pragma unroll
        for (int j = 0; j < 8; j++) pk[j] = (__bf16)fb[(size_t)(cg * 8 + j) * IPIX];
        *(bf16x8*)(op + cg * 8) = pk;
    }
}

// ---------------- K1: conv as implicit GEMM; weights LDS double-buffered ----------------
// Block: 256 thr = 4 waves; pixel tile 32 wide x 4 high; wave w = row w, 2 N-frags of 16.
// LDS: sh feature tile 29376 B + wlds weight dbuf 10240 B = 39616 B -> 4 blocks/CU.
__global__ __launch_bounds__(256, 4) void k_conv(const __bf16* __restrict__ fpk,
        const float* __restrict__ d00, const __bf16* __restrict__ wpk,
        const float* __restrict__ s_all, const float* __restrict__ b_all,
        __bf16* __restrict__ aff_p, __bf16* __restrict__ attp, __bf16* __restrict__ maskp,
        float* __restrict__ stp) {
    __shared__ __bf16 sh[6 * 34 * 72];
    __shared__ __bf16 wlds[2 * 2560];
    const int tid = threadIdx.x;
    // XCD-aware swizzle: contiguous y-slabs per XCD for halo L2 locality
    int flat = blockIdx.x + 38 * (blockIdx.y + 64 * blockIdx.z);
    int nf = (flat & 7) * 608 + (flat >> 3);
    int bx = nf % 38; int r2 = nf / 38;
    const int x0 = bx * 32, y0 = (r2 & 63) * 4, b = r2 >> 6;

    // prefetch weight panel 0 (5120 B)
    {
        bf16x8 w0 = *(const bf16x8*)(wpk + (size_t)tid * 8);
        *(bf16x8*)(wlds + tid * 8) = w0;
        if (tid < 64) {
            bf16x8 w1 = *(const bf16x8*)(wpk + 2048 + (size_t)tid * 8);
            *(bf16x8*)(wlds + 2048 + tid * 8) = w1;
        }
    }
    // stage feature tile from packed bf16: fully coalesced dwordx4 + ds_write_b128
    for (int idx = tid; idx < 204 * 8; idx += 256) {
        int cg = idx & 7, pos = idx >> 3;
        int row = pos / 34, x = pos - row * 34;
        int gy = y0 + row - 1, gx = x0 + x - 1;
        bf16x8 pk;
#pragma unroll
        for (int j = 0; j < 8; j++) pk[j] = (__bf16)0.f;
        if (gy >= 0 && gy < HH && gx >= 0 && gx < WW)
            pk = *(const bf16x8*)(fpk + ((size_t)(b * IPIX + gy * WW + gx) << 6) + cg * 8);
        *(bf16x8*)(sh + pos * 72 + cg * 8) = pk;
    }
    __syncthreads();

    const int wave = tid >> 6, lane = tid & 63;
    const int n = lane & 15, g = lane >> 4;

    floatx4 acc[5][2];
#pragma unroll
    for (int t = 0; t < 5; t++)
#pragma unroll
        for (int q = 0; q < 2; q++) acc[t][q] = (floatx4)(0.f);

#pragma unroll
    for (int kk = 0; kk < 18; kk++) {
        // prefetch weight panel kk+1 into registers (1-2 coalesced 16B loads/thread)
        bf16x8 wt0, wt1;
        if (kk < 17) {
            wt0 = *(const bf16x8*)(wpk + (size_t)(kk + 1) * 2560 + tid * 8);
            if (tid < 64) wt1 = *(const bf16x8*)(wpk + (size_t)(kk + 1) * 2560 + 2048 + tid * 8);
        }
        const int tap = kk >> 1;
        const int dy = tap / 3 - 1, dx = tap % 3 - 1;
        const int c0 = (kk & 1) * 32 + g * 8;
        bf16x8 bfr[2];
        const int rowb = wave + 1 + dy;
        const int colb = 1 + dx + n;
#pragma unroll
        for (int q = 0; q < 2; q++)
            bfr[q] = *(const bf16x8*)(sh + ((rowb * 34) + colb + q * 16) * 72 + c0);
        bf16x8 afr[5];
        const __bf16* wb = wlds + (kk & 1) * 2560 + lane * 8;
#pragma unroll
        for (int t = 0; t < 5; t++) afr[t] = *(const bf16x8*)(wb + t * 512);
#pragma unroll
        for (int t = 0; t < 5; t++)
#pragma unroll
            for (int q = 0; q < 2; q++)
                acc[t][q] = __builtin_amdgcn_mfma_f32_16x16x32_bf16(afr[t], bfr[q], acc[t][q], 0, 0, 0);
        if (kk < 17) {
            *(bf16x8*)(wlds + ((kk + 1) & 1) * 2560 + tid * 8) = wt0;
            if (tid < 64) *(bf16x8*)(wlds + ((kk + 1) & 1) * 2560 + 2048 + tid * 8) = wt1;
        }
        __syncthreads();
    }

    // phase 1: scale/bias + stats; bf16 results into LDS sh[m*132 + wave*32 + n + 16q]
    const int pix_base = b * IPIX + (y0 + wave) * WW + x0 + n;
    float p7[2] = {0,0}, t7[2] = {0,0};
    float p5[2] = {0,0}, t5[2] = {0,0};
    float p3[2] = {0,0}, t3[2] = {0,0};

#pragma unroll
    for (int t = 0; t < 5; t++) {
        const floatx4 sv = *(const floatx4*)(s_all + t * 16 + 4 * g);
        const floatx4 bv = *(const floatx4*)(b_all + t * 16 + 4 * g);
#pragma unroll
        for (int q = 0; q < 2; q++) {
#pragma unroll
            for (int reg = 0; reg < 4; reg++) {
                const int m = t * 16 + 4 * g + reg;
                const float v = fmaf(acc[t][q][reg], sv[reg], bv[reg]);
                if (m < 24)                { p7[q] += fabsf(v); t7[q] += v; }
                else if (m < 40)           { p5[q] += fabsf(v); t5[q] += v; }
                else if (m < 48)           { p3[q] += fabsf(v); t3[q] += v; }
                const float outv = (m < 48) ? v : sigm(v);
                sh[m * 132 + wave * 32 + n + q * 16] = (__bf16)outv;
            }
        }
    }
#pragma unroll
    for (int q = 0; q < 2; q++) {
        p7[q] += __shfl_xor(p7[q], 16); p7[q] += __shfl_xor(p7[q], 32);
        t7[q] += __shfl_xor(t7[q], 16); t7[q] += __shfl_xor(t7[q], 32);
        p5[q] += __shfl_xor(p5[q], 16); p5[q] += __shfl_xor(p5[q], 32);
        t5[q] += __shfl_xor(t5[q], 16); t5[q] += __shfl_xor(t5[q], 32);
        p3[q] += __shfl_xor(p3[q], 16); p3[q] += __shfl_xor(p3[q], 32);
        t3[q] += __shfl_xor(t3[q], 16); t3[q] += __shfl_xor(t3[q], 32);
    }
    if (g == 0) {
#pragma unroll
        for (int q = 0; q < 2; q++) {
            const int pixq = pix_base + q * 16;
            floatx4 s0 = {p7[q], p5[q], p3[q], t7[q]};
            floatx4 s1 = {t5[q], t3[q], 0.f, 0.f};
            *(floatx4*)(stp + (size_t)pixq * 8)     = s0;
            *(floatx4*)(stp + (size_t)pixq * 8 + 4) = s1;
        }
    }
    __syncthreads();

    // phase 2: transpose-read, fully coalesced stores
    const int px = tid & 127;
    const int grp = tid >> 7;
    const int prow = px >> 5, pcol = px & 31;
    const size_t ppx = (size_t)b * PPIX + (y0 + prow + 3) * PW + (x0 + pcol + XOFF);
    const int pix = b * IPIX + (y0 + prow) * WW + x0 + pcol;
#pragma unroll
    for (int m = 0; m < 48; m += 2) {
        aff_p[(size_t)(m + grp) * PLSTRIDE + ppx] = sh[(m + grp) * 132 + px];
    }
    const float d00v = d00[pix];
    const float valid = (d00v > 0.f) ? 1.f : 0.f;
#pragma unroll
    for (int j = 0; j < 6; j += 2) {
        const int it = j + grp;
        bf16x4 av = { sh[(48 + it) * 132 + px], sh[(54 + it) * 132 + px],
                      sh[(60 + it) * 132 + px], sh[(66 + it) * 132 + px] };
        *(bf16x4*)(attp + ((size_t)it * NPIX + pix) * 4) = av;
        maskp[(size_t)it * NPIX + pix] = (__bf16)((float)sh[(72 + it) * 132 + px] * valid);
    }
}

// ---------------- K2 (once): per-pixel, per-iter guide ratios r_k and g0*d0 ----------------
__global__ __launch_bounds__(256) void k_rg(const __bf16* __restrict__ attp,
        const float* __restrict__ stp, const float* __restrict__ d0,
        _Float16* __restrict__ rp, float* __restrict__ gd) {
    int g = blockIdx.x * blockDim.x + threadIdx.x;
    if (g >= NPIX) return;
    const floatx4 s0 = *(const floatx4*)(stp + (size_t)g * 8);
    const floatx4 s1 = *(const floatx4*)(stp + (size_t)g * 8 + 4);
    const float S7 = s0[0], S5 = s0[1], S3 = s0[2], T7 = s0[3], T5 = s1[0], T3 = s1[1];
    const float d0v = d0[g];
#pragma unroll
    for (int it = 0; it < 6; it++) {
        bf16x4 a = *(const bf16x4*)(attp + ((size_t)it * NPIX + g) * 4);
        float a7 = (float)a[0], a5 = (float)a[1], a3 = (float)a[2], a1 = (float)a[3];
        float denom = a7 * S7 + a5 * S5 + a3 * S3 + a1;   // > 0: a1 = sigmoid > 0
        float inv = 1.f / denom;
        float r7 = a7 * inv, r5 = a5 * inv, r3 = a3 * inv, r1 = a1 * inv;
        float g0 = 1.f - (r7 * T7 + r5 * T5 + r3 * T3 + r1);
        half4 rv = {(_Float16)r7, (_Float16)r5, (_Float16)r3, (_Float16)r1};
        *(half4*)(rp + ((size_t)it * NPIX + g) * 4) = rv;
        gd[(size_t)it * NPIX + g] = g0 * d0v;
    }
}

// ---------------- K3 (per iter): LDS p-planes + batched 49-tap gather ----------------
__global__ __launch_bounds__(256) void k_iter(const _Float16* __restrict__ rp,
        const float* __restrict__ gd, const float* __restrict__ dt,
        const __bf16* __restrict__ aff_p, const __bf16* __restrict__ maskp,
        const float* __restrict__ d00,
        float* __restrict__ dtn, int it) {
    __shared__ float sp[5][14 * 38];
    const int tid = threadIdx.x;
    const int tx = tid & 31, ty = tid >> 5;
    int flat = blockIdx.x + 38 * (blockIdx.y + 32 * blockIdx.z);
    int nf = (flat & 7) * 304 + (flat >> 3);
    int bx = nf % 38; int r2 = nf / 38;
    const int x0 = bx * 32, y0 = (r2 & 31) * 8, b = r2 >> 5;
    const int ib = b * IPIX;

    for (int idx = tid; idx < 14 * 38; idx += 256) {
        int r = idx / 38, col = idx - r * 38;
        int gy = y0 + r - 3, gx = x0 + col - 3;
        float v7 = 0.f, v5 = 0.f, v3 = 0.f, v1 = 0.f, vb = 0.f;
        if (gy >= 0 && gy < HH && gx >= 0 && gx < WW) {
            int q = ib + gy * WW + gx;
            half4 rv = *(const half4*)(rp + ((size_t)it * NPIX + q) * 4);
            float dtv = dt[q];
            v7 = (float)rv[0] * dtv; v5 = (float)rv[1] * dtv;
            v3 = (float)rv[2] * dtv; v1 = (float)rv[3] * dtv;
            vb = gd[(size_t)it * NPIX + q];
        }
        sp[0][idx] = v7; sp[1][idx] = v5; sp[2][idx] = v3; sp[3][idx] = v1; sp[4][idx] = vb;
    }
    __syncthreads();

    const int y = y0 + ty, x = x0 + tx;
    const int pix = ib + y * WW + x;
    const __bf16* ap = aff_p + (size_t)b * PPIX + (y + 3) * PW + (x + XOFF);

    // center + base
    float acc0 = sp[4][(ty + 3) * 38 + (tx + 3)] + sp[3][(ty + 3) * 38 + (tx + 3)];
    float acc1 = 0.f, acc2 = 0.f, acc3 = 0.f;
    // 6 batches of 8: 8 aff loads in flight per waitcnt
#pragma unroll
    for (int bt = 0; bt < 6; bt++) {
        float a8[8];
#pragma unroll
        for (int j = 0; j < 8; j++) {
            const int t = TAPNC[bt * 8 + j];
            const int dy = 3 - t / 7, dx = 3 - (t % 7);
            a8[j] = (float)ap[(ptrdiff_t)PLANE[t] * PLSTRIDE + dy * PW + dx];
        }
#pragma unroll
        for (int j = 0; j < 8; j++) {
            const int t = TAPNC[bt * 8 + j];
            const int dy = 3 - t / 7, dx = 3 - (t % 7);
            const float pv = sp[KCLS[t]][(ty + dy + 3) * 38 + (tx + dx + 3)];
            switch (j & 3) {
                case 0: acc0 = fmaf(a8[j], pv, acc0); break;
                case 1: acc1 = fmaf(a8[j], pv, acc1); break;
                case 2: acc2 = fmaf(a8[j], pv, acc2); break;
                default: acc3 = fmaf(a8[j], pv, acc3); break;
            }
        }
    }
    float acc = (acc0 + acc1) + (acc2 + acc3);
    float m = (float)maskp[(size_t)it * NPIX + pix];
    float dtv = m * d00[pix] + (1.f - m) * acc;
    dtn[pix] = dtv;
}

// ---------------- launch ----------------
extern "C" void kernel_launch(void* const* d_in, const int* in_sizes, int n_in,
                              void* d_out, int out_size, void* d_ws, size_t ws_size,
                              hipStream_t stream) {
    const float* feat = (const float*)d_in[0];
    const float* d0   = (const float*)d_in[1];
    const float* d00  = (const float*)d_in[2];
    WPtrs wp;
    for (int l = 0; l < 8; l++) {
        wp.w[l] = (const float*)d_in[3 + 3 * l];
        wp.s[l] = (const float*)d_in[4 + 3 * l];
        wp.b[l] = (const float*)d_in[5 + 3 * l];
    }
    __bf16*   wsb   = (__bf16*)d_ws;
    __bf16*   aff_p = wsb;                                   // 48 padded planes bf16
    __bf16*   attp  = aff_p + (size_t)48 * PLSTRIDE;         // 6*NPIX bf16x4
    __bf16*   msk_b = attp + (size_t)24 * NPIX;              // 6 planes bf16
    float*    stp   = (float*)(msk_b + (size_t)6 * NPIX);    // NPIX*8 fp32
    float*    dtA   = stp + (size_t)8 * NPIX;                // 1 fp32 plane (ping)
    __bf16*   wpk   = (__bf16*)(dtA + (size_t)NPIX);         // 92160 B packed weights
    float*    s_all = (float*)(wpk + 18 * 5 * 64 * 8);
    float*    b_all = s_all + 80;
    // region X: fpk (dead after k_conv) aliased over rp+gd (written after, by k_rg)
    char*     X     = (char*)(b_all + 80);
    __bf16*   fpk   = (__bf16*)X;                            // 64*NPIX bf16 (79.7 MB)
    _Float16* rp    = (_Float16*)X;                          // 6*NPIX fp16x4
    float*    gd    = (float*)(X + (size_t)24 * NPIX * 2);   // 6*NPIX fp32
    float*    dtB   = (float*)d_out;                         // pong (overwritten before reads)

    hipLaunchKernelGGL(k_pack, dim3(23), dim3(256), 0, stream, wp, wpk, s_all, b_all);
    hipLaunchKernelGGL(k_zero_pad, dim3((48 * BB * (6 * PW + 256 * 16) + 255) / 256), dim3(256),
                       0, stream, aff_p);
    hipLaunchKernelGGL(k_cvt, dim3(WW / 64, HH, BB), dim3(256), 0, stream, feat, fpk);
    hipLaunchKernelGGL(k_conv, dim3(38, 64, 2), dim3(256), 0, stream,
                       fpk, d00, wpk, s_all, b_all, aff_p, attp, msk_b, stp);
    hipLaunchKernelGGL(k_rg, dim3(NPIX / 256), dim3(256), 0, stream,
                       attp, stp, d0, rp, gd);
    const float* cur = d0;
    for (int it = 0; it < 6; ++it) {
        float* nxt = (it & 1) ? dtB : dtA;
        if (it == 5) nxt = dtB;
        hipLaunchKernelGGL(k_iter, dim3(38, 32, 2), dim3(256), 0, stream,
                           rp, gd, cur, aff_p, msk_b, d00, nxt, it);
        cur = nxt;
    }
}